// Round 3
// baseline (73.138 us; speedup 1.0000x reference)
//
#include <hip/hip_runtime.h>

#define Bc 2
#define Hc 32
#define N1c 1024
#define Nc 1023
#define BLOCK 256
#define LDSW 40   // ushorts per LDS row (80 B): conflict-free, 16B-aligned rows

typedef __attribute__((ext_vector_type(8))) short bf16x8;
typedef __attribute__((ext_vector_type(4))) float f32x4;

__device__ __forceinline__ unsigned short f2bf(float a) {
    unsigned ua = __float_as_uint(a);
    ua = (ua + 0x7fffu + ((ua >> 16) & 1u)) >> 16;
    return (unsigned short)ua;
}

// packed f32x2 -> bf16x2 (RNE), single VALU op
__device__ __forceinline__ unsigned cvt_pk_bf16(float lo, float hi) {
    unsigned r;
    asm("v_cvt_pk_bf16_f32 %0, %1, %2" : "=v"(r) : "v"(lo), "v"(hi));
    return r;
}

__global__ __launch_bounds__(BLOCK) void se3_head_kernel(
    const float* __restrict__ x,    // [B,N,3]
    const float* __restrict__ qk,   // [B,H,N1,N1]
    const float* __restrict__ W1,   // [H,H]
    const float* __restrict__ b1,   // [H]
    const float* __restrict__ W2,   // [1,H]
    const float* __restrict__ b2,   // [1]
    float* __restrict__ out)        // [B,N,3]
{
    __shared__ unsigned short qs[4][64][LDSW];  // per-wave private strip, single-buffered
    __shared__ float xs[N1c][3];                // x staged once (row 1023 zeroed)
    __shared__ float red[4][4];

    const int bi   = blockIdx.x;
    const int b    = bi / Nc;
    const int i    = bi % Nc;
    const int t    = threadIdx.x;
    const int w    = t >> 6;
    const int lane = t & 63;
    const int lrow = lane & 15;   // A-row-within-16 / C-col (g)
    const int lk   = lane >> 4;   // k-chunk / C-row-quad

    const float* qk_b = qk + (size_t)b * Hc * N1c * N1c + (size_t)(i + 1) * N1c;
    const float* xb   = x + (size_t)b * Nc * 3;

    // ---- stage x into LDS once (row 1023 = zeros for the tail slot) ----
    #pragma unroll
    for (int rr = t; rr < N1c; rr += BLOCK) {
        float v0 = 0.f, v1 = 0.f, v2 = 0.f;
        if (rr < Nc) { v0 = xb[rr*3]; v1 = xb[rr*3+1]; v2 = xb[rr*3+2]; }
        xs[rr][0] = v0; xs[rr][1] = v1; xs[rr][2] = v2;
    }

    // ---- per-lane constants: W1 pre-scaled by w2 (sign folded via med3 limit) ----
    const float w2a = W2[lrow], w2b = W2[lrow + 16];
    bf16x8 B0, B1;
    #pragma unroll
    for (int e = 0; e < 8; ++e) {
        ((unsigned short*)&B0)[e] = f2bf(W1[lrow * Hc + lk * 8 + e] * w2a);
        ((unsigned short*)&B1)[e] = f2bf(W1[(lrow + 16) * Hc + lk * 8 + e] * w2b);
    }
    const float bw0 = b1[lrow] * w2a, bw1 = b1[lrow + 16] * w2b;
    const f32x4 cb0 = {bw0, bw0, bw0, bw0};
    const f32x4 cb1 = {bw1, bw1, bw1, bw1};
    const float lim0 = (w2a >= 0.f) ? __builtin_inff() : -__builtin_inff();
    const float lim1 = (w2b >= 0.f) ? __builtin_inff() : -__builtin_inff();
    const float b2s  = b2[0] * (1.0f / 16.0f);   // 16 lanes (g-cols) sum per j

    __syncthreads();   // xs visible; only barrier before the end

    float S = 0.f, T0 = 0.f, T1 = 0.f, T2 = 0.f;
    float v[Hc];

    // issue strip-k loads (wave-private strip sw = w*4+k); saddr form per h
    auto L = [&](int k) {
        const int sw = w * 4 + k;
        int jj = sw * 64 + lane;
        jj = jj > Nc - 1 ? Nc - 1 : jj;    // clamp j=1023 -> 1022 (masked later)
        const int joff = jj + 1;
        #pragma unroll
        for (int h = 0; h < Hc; ++h)
            v[h] = *(qk_b + (size_t)h * N1c * N1c + joff);
    };

    auto STAGE = [&]() {
        #pragma unroll
        for (int q = 0; q < 4; ++q) {
            uint4 pkt;
            pkt.x = cvt_pk_bf16(v[q*8+0], v[q*8+1]);
            pkt.y = cvt_pk_bf16(v[q*8+2], v[q*8+3]);
            pkt.z = cvt_pk_bf16(v[q*8+4], v[q*8+5]);
            pkt.w = cvt_pk_bf16(v[q*8+6], v[q*8+7]);
            *reinterpret_cast<uint4*>(&qs[w][lane][q*8]) = pkt;
        }
    };

    auto COMP = [&](int k) {
        const int sw = w * 4 + k;
        #pragma unroll
        for (int m = 0; m < 4; ++m) {
            bf16x8 A = *reinterpret_cast<const bf16x8*>(&qs[w][m*16 + lrow][lk*8]);
            f32x4 c0 = __builtin_amdgcn_mfma_f32_16x16x32_bf16(A, B0, cb0, 0, 0, 0);
            f32x4 c1 = __builtin_amdgcn_mfma_f32_16x16x32_bf16(A, B1, cb1, 0, 0, 0);
            const int jb = sw * 64 + m * 16 + lk * 4;
            const float* xp = &xs[jb][0];
            f32x4 xA = *reinterpret_cast<const f32x4*>(xp);
            f32x4 xB = *reinterpret_cast<const f32x4*>(xp + 4);
            f32x4 xC = *reinterpret_cast<const f32x4*>(xp + 8);
            const float xj[4][3] = {{xA.x, xA.y, xA.z}, {xA.w, xB.x, xB.y},
                                    {xB.z, xB.w, xC.x}, {xC.y, xC.z, xC.w}};
            #pragma unroll
            for (int r = 0; r < 4; ++r) {
                float t0 = __builtin_amdgcn_fmed3f(c0[r], 0.f, lim0); // relu*w2 (sign folded)
                float t1 = __builtin_amdgcn_fmed3f(c1[r], 0.f, lim1);
                float cp = t0 + t1 + b2s;
                if (sw == 15 && m == 3)                    // only j=1023 is invalid
                    cp = (jb + r < Nc) ? cp : 0.f;
                S += cp;
                T0 = fmaf(xj[r][0], cp, T0);
                T1 = fmaf(xj[r][1], cp, T1);
                T2 = fmaf(xj[r][2], cp, T2);
            }
        }
    };

    L(0);
    #pragma unroll
    for (int k = 0; k < 4; ++k) {
        STAGE();                 // waits L(k), cvt_pk, 4x ds_write_b128
        if (k < 3) L(k + 1);     // prefetch next strip under compute(k)
        COMP(k);                 // wave-private LDS: no barrier needed
    }

    // ---- block reduction ----
    #pragma unroll
    for (int off = 32; off > 0; off >>= 1) {
        S  += __shfl_down(S,  off);
        T0 += __shfl_down(T0, off);
        T1 += __shfl_down(T1, off);
        T2 += __shfl_down(T2, off);
    }
    if (lane == 0) { red[w][0] = S; red[w][1] = T0; red[w][2] = T1; red[w][3] = T2; }
    __syncthreads();

    if (t == 0) {
        float s = 0.f, u0 = 0.f, u1 = 0.f, u2 = 0.f;
        #pragma unroll
        for (int q = 0; q < 4; ++q) {
            s += red[q][0]; u0 += red[q][1]; u1 += red[q][2]; u2 += red[q][3];
        }
        const float xi0 = xs[i][0], xi1 = xs[i][1], xi2 = xs[i][2];
        out[(b*Nc + i)*3 + 0] = fmaf(xi0, s, xi0) - u0;
        out[(b*Nc + i)*3 + 1] = fmaf(xi1, s, xi1) - u1;
        out[(b*Nc + i)*3 + 2] = fmaf(xi2, s, xi2) - u2;
    }
}

extern "C" void kernel_launch(void* const* d_in, const int* in_sizes, int n_in,
                              void* d_out, int out_size, void* d_ws, size_t ws_size,
                              hipStream_t stream) {
    const float* x  = (const float*)d_in[0];
    const float* qk = (const float*)d_in[1];
    const float* W1 = (const float*)d_in[2];
    const float* b1 = (const float*)d_in[3];
    const float* W2 = (const float*)d_in[4];
    const float* b2 = (const float*)d_in[5];
    float* out = (float*)d_out;

    se3_head_kernel<<<dim3(Bc * Nc), dim3(BLOCK), 0, stream>>>(
        x, qk, W1, b1, W2, b2, out);
}